// Round 2
// baseline (738.601 us; speedup 1.0000x reference)
//
#include <hip/hip_runtime.h>

// SkeletalEncBlock: masked skeletal conv1d(K=3,'same') + offset inject + pair pool + LeakyReLU(0.2)
// x:      [B=128, 192, T=4096] fp32
// offset: [B, 72]
// W:      [192, 192, 3]
// b:      [192]
// W_off:  [192, 72]
// out:    [B, 96, T]
//
// Fold pair-pooling + adjacency mask into effective weights per region r:
//   out[b, r*8+o, t] = LReLU( sum_{c,k} Weff[c][o][k] * x[b, c0+c, t+k-1] + Beff[b,r,o] )
// where the input span of region r is <=4 joints = 32 channels (contiguous).

#define NJ    24
#define NCIN  8
#define NCOUT 8
#define KS    3
#define NB    128
#define NT    4096
#define NREG  12
#define VT    8            // t-values per thread
#define LANES 128          // t-threads per block
#define TPB   256          // LANES * 2 o-groups (o 0..3 / 4..7)
#define TILE  (LANES * VT) // 1024
#define NTILES (NT / TILE) // 4
#define NCH   32           // padded channel span per region
#define NEG_SLOPE 0.2f

__global__ __launch_bounds__(TPB) void skel_enc_kernel(
    const float* __restrict__ x,
    const float* __restrict__ offset,
    const float* __restrict__ W,
    const float* __restrict__ bias,
    const float* __restrict__ Woff,
    float* __restrict__ out)
{
    const int tile = blockIdx.x;
    const int r    = blockIdx.y;
    const int b    = blockIdx.z;
    const int tid  = threadIdx.x;

    const int j0 = 2 * r, j1 = 2 * r + 1;
    const int jlo  = (j0 - 1 > 0) ? (j0 - 1) : 0;
    const int jhi  = (j1 + 1 < NJ - 1) ? (j1 + 1) : (NJ - 1);
    const int ncin = (jhi - jlo + 1) * NCIN;   // 24 or 32
    const int c0   = jlo * NCIN;

    __shared__ float sW[NCH * 24];   // [c][o*3+k] pooled+masked effective weights
    __shared__ float sBias[NCOUT];

    // ---- zero sW (two accumulate passes follow) ----
    for (int idx = tid; idx < NCH * 24; idx += TPB) sW[idx] = 0.f;
    __syncthreads();

    // ---- stage effective weights, coalesced: per joint-row, 96 contiguous floats ----
    for (int jj = 0; jj < 2; ++jj) {
        const int j = j0 + jj;
        for (int idx = tid; idx < NCOUT * 96; idx += TPB) {   // 768
            const int o   = idx / 96;
            const int pos = idx - o * 96;      // pos = c*3 + k, contiguous in W
            const int c   = pos / 3;
            const int k   = pos - 3 * c;
            const int gj  = jlo + (c >> 3);
            float val = 0.f;
            if (c < ncin && gj >= j - 1 && gj <= j + 1)
                val = 0.5f * W[(size_t)(j * NCOUT + o) * (192 * 3) + (size_t)(c0 + c) * 3 + k];
            sW[c * 24 + o * 3 + k] += val;     // (c,o,k) unique within pass
        }
        __syncthreads();
    }

    // ---- pooled bias + masked offset injection (per b,r; 8 threads) ----
    if (tid < NCOUT) {
        const int o = tid;
        float acc0 = 0.5f * (bias[j0 * NCOUT + o] + bias[j1 * NCOUT + o]);
        const float* offb = offset + (size_t)b * (NJ * 3);
        const int ilo = ((j0 - 1 > 0) ? (j0 - 1) : 0) * 3;
        const int jtop = (j1 + 1 < NJ - 1) ? (j1 + 1) : (NJ - 1);
        const int ihi = (jtop + 1) * 3;
        float s = 0.f;
        for (int i = ilo; i < ihi; ++i) {
            const int ji = i / 3;
            const float ov = offb[i];
            float w = 0.f;
            if (ji >= j0 - 1 && ji <= j0 + 1) w += Woff[(size_t)(j0 * NCOUT + o) * (NJ * 3) + i];
            if (ji >= j1 - 1 && ji <= j1 + 1) w += Woff[(size_t)(j1 * NCOUT + o) * (NJ * 3) + i];
            s += w * ov;
        }
        sBias[o] = acc0 + 0.5f * s;
    }
    __syncthreads();

    // ---- main conv: 128 t-lanes x 2 o-groups; thread owns 8 t's x 4 o's ----
    const int lane = tid & (LANES - 1);
    const int ob   = (tid >> 7) * 4;          // 0 or 4
    const int t0   = tile * TILE + lane * VT;

    float acc[4][VT];
    #pragma unroll
    for (int ol = 0; ol < 4; ++ol) {
        const float bv = sBias[ob + ol];
        #pragma unroll
        for (int v = 0; v < VT; ++v) acc[ol][v] = bv;
    }

    const float* xb = x + (size_t)b * (NJ * NCIN) * NT + t0;
    const bool has_lo = (t0 > 0);
    const bool has_hi = (t0 + VT < NT);

    #pragma unroll 1
    for (int c = 0; c < NCH; ++c) {
        const int gc = (c0 + c < 191) ? (c0 + c) : 191;   // clamp; padded channels have w=0
        const float* xp = xb + (size_t)gc * NT;

        float xv[VT + 2];
        const float4 a0 = *reinterpret_cast<const float4*>(xp);
        const float4 a1 = *reinterpret_cast<const float4*>(xp + 4);
        xv[1] = a0.x; xv[2] = a0.y; xv[3] = a0.z; xv[4] = a0.w;
        xv[5] = a1.x; xv[6] = a1.y; xv[7] = a1.z; xv[8] = a1.w;
        const float xm = xp[has_lo ? -1 : 0];
        xv[0] = has_lo ? xm : 0.f;
        const float xq = xp[has_hi ? VT : VT - 1];
        xv[VT + 1] = has_hi ? xq : 0.f;

        const int wbase = c * 24 + ob * 3;
        #pragma unroll
        for (int ol = 0; ol < 4; ++ol) {
            #pragma unroll
            for (int k = 0; k < KS; ++k) {
                const float wv = sW[wbase + ol * 3 + k];   // LDS broadcast read
                #pragma unroll
                for (int v = 0; v < VT; ++v)
                    acc[ol][v] = fmaf(wv, xv[v + k], acc[ol][v]);
            }
        }
    }

    // ---- LeakyReLU + coalesced float4 stores ----
    float* obase = out + ((size_t)b * (NREG * NCOUT) + (size_t)(r * NCOUT + ob)) * NT + t0;
    #pragma unroll
    for (int ol = 0; ol < 4; ++ol) {
        float4 s0, s1;
        s0.x = acc[ol][0] > 0.f ? acc[ol][0] : NEG_SLOPE * acc[ol][0];
        s0.y = acc[ol][1] > 0.f ? acc[ol][1] : NEG_SLOPE * acc[ol][1];
        s0.z = acc[ol][2] > 0.f ? acc[ol][2] : NEG_SLOPE * acc[ol][2];
        s0.w = acc[ol][3] > 0.f ? acc[ol][3] : NEG_SLOPE * acc[ol][3];
        s1.x = acc[ol][4] > 0.f ? acc[ol][4] : NEG_SLOPE * acc[ol][4];
        s1.y = acc[ol][5] > 0.f ? acc[ol][5] : NEG_SLOPE * acc[ol][5];
        s1.z = acc[ol][6] > 0.f ? acc[ol][6] : NEG_SLOPE * acc[ol][6];
        s1.w = acc[ol][7] > 0.f ? acc[ol][7] : NEG_SLOPE * acc[ol][7];
        float* op = obase + (size_t)ol * NT;
        *reinterpret_cast<float4*>(op)     = s0;
        *reinterpret_cast<float4*>(op + 4) = s1;
    }
}

extern "C" void kernel_launch(void* const* d_in, const int* in_sizes, int n_in,
                              void* d_out, int out_size, void* d_ws, size_t ws_size,
                              hipStream_t stream) {
    const float* x      = (const float*)d_in[0];
    const float* offset = (const float*)d_in[1];
    const float* W      = (const float*)d_in[2];
    const float* bias   = (const float*)d_in[3];
    const float* Woff   = (const float*)d_in[4];
    float* out = (float*)d_out;

    dim3 grid(NTILES, NREG, NB);
    skel_enc_kernel<<<grid, TPB, 0, stream>>>(x, offset, W, bias, Woff, out);
}